// Round 9
// baseline (1192.116 us; speedup 1.0000x reference)
//
#include <hip/hip_runtime.h>
#include <hip/hip_fp16.h>

#define LDIM 50
#define MBIN 262144
#define ODIM 155
#define VOCABSZ 100

// ---- workspace layout (produced by precompute_kernel; same as round 8) ----
// half-indexed (from (__half*)ws), occupying float [0..20000):
#define H_T   0        // 30000 halves : T[s][v][d] fp16 (s=0 pe-slot, b_pred folded; s=1..5 ve)
#define H_PE  30000    // 5000 halves  : pe fp16
#define H_VE  35000    // 5000 halves  : ve fp16
// float-indexed:
#define F_LG  20000    // 300 : attention logits fp32
#define F_TB  20304    // 5000 : (oe @ W_bin[50:100] + b_bin) fp32 (read from global, L2-hot)

// ---- static LDS (floats), 39936 = 159744 B -> 1 WG/CU, 16 waves ----
// [0..20000)      fp16 tables (staging + build phase)
// [20000..20304)  lg fp32 (dead after scalars)
// after build:  stashA h2[0..12800)  = floats [0..12800)    (hA -> h_bin -> h_q)
//               stashB h2[12800..25600) = floats [12800..25600) (hB -> h_un)
// [25600..27648)  lred: logit partials (2 arrays x 2 pi x 512)  (dead early)
// [25600..39936)  sw: 16 waves x 64 x 14 store-transpose (W_fin only, overlays lred)
#define O_LRED 25600
#define O_SW   25600
#define LDS_FLOATS 39936

// ---------------------------------------------------------------------------
// Precompute (identical to round 8 — proven)
// ---------------------------------------------------------------------------
__global__ __launch_bounds__(64) void precompute_kernel(
    const float* __restrict__ pe, const float* __restrict__ ve, const float* __restrict__ oe,
    const float* __restrict__ W_pred, const float* __restrict__ b_pred,
    const float* __restrict__ W_bin, const float* __restrict__ b_bin,
    const float* __restrict__ W_att, const float* __restrict__ b_att,
    float* __restrict__ ws)
{
    __half* wsh = (__half*)ws;
    const int bid = blockIdx.x;
    const int t = threadIdx.x;
    if (bid < 600) {
        const int s = bid / VOCABSZ, v = bid % VOCABSZ;
        if (t < LDIM) {
            const float* E = (s == 0) ? pe : ve;
            float acc = (s == 0) ? b_pred[t] : 0.0f;
            for (int e = 0; e < LDIM; ++e)
                acc += E[v*LDIM + e] * W_pred[(s*LDIM + e)*LDIM + t];
            wsh[H_T + (s*VOCABSZ + v)*LDIM + t] = __float2half_rn(acc);
        }
    } else if (bid < 700) {
        const int v = bid - 600;
        if (t < LDIM) {
            float acc = b_bin[t];
            for (int e = 0; e < LDIM; ++e)
                acc += oe[v*LDIM + e] * W_bin[(LDIM + e)*LDIM + t];
            ws[F_TB + v*LDIM + t] = acc;
        }
    } else if (bid < 800) {
        const int v = bid - 700;
        if (t < LDIM) wsh[H_PE + v*LDIM + t] = __float2half_rn(pe[v*LDIM + t]);
    } else if (bid < 900) {
        const int v = bid - 800;
        if (t < LDIM) wsh[H_VE + v*LDIM + t] = __float2half_rn(ve[v*LDIM + t]);
    } else {
        const int g = (bid - 900)*64 + t;
        if (g < 300) {
            const int which = g / VOCABSZ, v = g % VOCABSZ;
            const float* E = (which == 0) ? pe : ((which == 1) ? ve : oe);
            float acc = b_att[0];
            for (int e = 0; e < LDIM; ++e)
                acc += E[v*LDIM + e] * W_att[e];
            ws[F_LG + g] = acc;
        }
    }
}

// ---------------------------------------------------------------------------
// h pair (dims 2i, 2i+1) of a predicate node from fp16 LDS tables (round 8)
// ---------------------------------------------------------------------------
__device__ __forceinline__ float2 node_h_i(
    int i, int p, const int* __restrict__ v,
    float e0, const float* __restrict__ ek, float inv,
    const __half* __restrict__ ldsh)
{
    const __half2* T2  = (const __half2*)(ldsh + H_T);
    const __half2* pe2 = (const __half2*)(ldsh + H_PE);
    const __half2* ve2 = (const __half2*)(ldsh + H_VE);
    float2 lin = __half22float2(T2[p*(LDIM/2) + i]);
    float2 pv  = __half22float2(pe2[p*(LDIM/2) + i]);
    float nx = e0*pv.x, ny = e0*pv.y;
#pragma unroll
    for (int s = 0; s < 5; ++s) {
        float2 a = __half22float2(T2[((s+1)*VOCABSZ + v[s])*(LDIM/2) + i]);
        float2 b = __half22float2(ve2[v[s]*(LDIM/2) + i]);
        lin.x += a.x; lin.y += a.y;
        nx += ek[s]*b.x; ny += ek[s]*b.y;
    }
    return make_float2(fmaxf(lin.x, 0.0f) + nx*inv,
                       fmaxf(lin.y, 0.0f) + ny*inv);
}

// ---------------------------------------------------------------------------
// Per-wave work, PI = wave parity (compile-time): dims [26*PI, 26*PI+26-2*PI)
// All loop bounds compile-time; all weight bases wave-uniform (s_load streams).
// ---------------------------------------------------------------------------
template<int PI>
__device__ __forceinline__ void work(
    int nl, int lane, int wave, int pairid, int blockbase,
    int pA, int pB, const int* __restrict__ vA, const int* __restrict__ vB, int op,
    float e0A, float e0B, const float* __restrict__ ekA, const float* __restrict__ ekB,
    float invA, float invB, float w1, float batt,
    float* __restrict__ ldsf, const __half* __restrict__ ldsh,
    const float* __restrict__ oe,
    const float* __restrict__ W_bin, const float* __restrict__ W_un,
    const float* __restrict__ b_un, const float* __restrict__ W_univ,
    const float* __restrict__ b_univ, const float* __restrict__ W_att,
    const float* __restrict__ W_fin, const float* __restrict__ b_fin,
    const float* __restrict__ ws, float* __restrict__ out)
{
    constexpr int NI   = 13 - PI;    // own h2-pairs: PI=0 -> 13 (dims 0..25), PI=1 -> 12 (26..49)
    constexpr int IOFF = 13 * PI;
    constexpr int DOFF = 26 * PI;

    // ---- build own dim-range of hA,hB (packed fp16 regs) + logit partials ----
    __half2 hA2[NI], hB2[NI];
    float lApart = (PI == 0) ? batt : 0.0f;
    float lBpart = (PI == 0) ? batt : 0.0f;
#pragma unroll
    for (int ii = 0; ii < NI; ++ii) {
        const int i = ii + IOFF;
        float2 a = node_h_i(i, pA, vA, e0A, ekA, invA, ldsh);
        float2 b = node_h_i(i, pB, vB, e0B, ekB, invB, ldsh);
        hA2[ii] = __floats2half2_rn(a.x, a.y);
        hB2[ii] = __floats2half2_rn(b.x, b.y);
        lApart += a.x*W_att[2*i] + a.y*W_att[2*i+1];
        lBpart += b.x*W_att[2*i] + b.y*W_att[2*i+1];
    }
    // logit partials -> lred
    ldsf[O_LRED + PI*512 + nl]        = lApart;
    ldsf[O_LRED + 1024 + PI*512 + nl] = lBpart;
    __syncthreads();                       // B2: builds done (tables dead), lred ready

    const float lA = lApart + ldsf[O_LRED + (1-PI)*512 + nl];
    const float lB = lBpart + ldsf[O_LRED + 1024 + (1-PI)*512 + nl];
    const float w0 = __expf(lA), w2 = __expf(lB);
    const float inv2 = 1.0f / (w0 + w1 + w2);

    // ---- stash hA,hB (fp16) over the dead table region ----
    __half2* stA = reinterpret_cast<__half2*>(ldsf);   // h2 [0..12800)
    __half2* stB = stA + 12800;                        // h2 [12800..25600)
#pragma unroll
    for (int ii = 0; ii < NI; ++ii) {
        stA[nl*25 + IOFF + ii] = hA2[ii];
        stB[nl*25 + IOFF + ii] = hB2[ii];
    }
    __syncthreads();                       // B3: full hA/hB visible

    // ---- pass 2: lin2(own dims) = hA @ Wbin[0:50] + hB @ Wbin[100:150] ----
    float lin2[2*NI];
#pragma unroll
    for (int ii = 0; ii < 2*NI; ++ii) lin2[ii] = 0.0f;
    {
        const float* Wb = W_bin + DOFF;
#pragma unroll
        for (int ie = 0; ie < 25; ++ie) {
            const float2 ha = __half22float2(stA[nl*25 + ie]);
            const float2 hb = __half22float2(stB[nl*25 + ie]);
            const float* wa0 = Wb + (2*ie)*LDIM;
            const float* wa1 = wa0 + LDIM;
            const float* wb0 = Wb + (2*LDIM + 2*ie)*LDIM;
            const float* wb1 = wb0 + LDIM;
#pragma unroll
            for (int ii = 0; ii < NI; ++ii) {
                lin2[2*ii]   += ha.x*wa0[2*ii]   + ha.y*wa1[2*ii]
                              + hb.x*wb0[2*ii]   + hb.y*wb1[2*ii];
                lin2[2*ii+1] += ha.x*wa0[2*ii+1] + ha.y*wa1[2*ii+1]
                              + hb.x*wb0[2*ii+1] + hb.y*wb1[2*ii+1];
            }
        }
    }

    // ---- h_bin(own dims): relu(lin2+Tb[op]) + (w0*hA + w2*hB + w1*oe[op])*inv2 ----
    __half2 h2o[NI];
    {
        const float2* Tb2 = (const float2*)(ws + F_TB + op*LDIM + DOFF);
        const float2* oe2 = (const float2*)(oe + op*LDIM + DOFF);
#pragma unroll
        for (int ii = 0; ii < NI; ++ii) {
            const float2 t = Tb2[ii], o = oe2[ii];
            const float2 a = __half22float2(hA2[ii]);
            const float2 b = __half22float2(hB2[ii]);
            const float hx = fmaxf(lin2[2*ii]   + t.x, 0.0f) + (w0*a.x + w2*b.x + w1*o.x)*inv2;
            const float hy = fmaxf(lin2[2*ii+1] + t.y, 0.0f) + (w0*a.y + w2*b.y + w1*o.y)*inv2;
            h2o[ii] = __floats2half2_rn(hx, hy);
        }
    }
    __syncthreads();                       // B4: all pass-2 stash reads done
#pragma unroll
    for (int ii = 0; ii < NI; ++ii) stA[nl*25 + IOFF + ii] = h2o[ii];   // h_bin -> stashA
    __syncthreads();                       // B5

    // ---- h_un(own) = relu(h_bin @ W_un + b_un) ----
    {
        float acc[2*NI];
        const float* bu = b_un + DOFF;
#pragma unroll
        for (int ii = 0; ii < 2*NI; ++ii) acc[ii] = bu[ii];
        const float* Wu = W_un + DOFF;
#pragma unroll
        for (int ie = 0; ie < 25; ++ie) {
            const float2 h = __half22float2(stA[nl*25 + ie]);
            const float* wr0 = Wu + (2*ie)*LDIM;
            const float* wr1 = wr0 + LDIM;
#pragma unroll
            for (int ii = 0; ii < 2*NI; ++ii)
                acc[ii] += h.x*wr0[ii] + h.y*wr1[ii];
        }
#pragma unroll
        for (int ii = 0; ii < NI; ++ii)
            h2o[ii] = __floats2half2_rn(fmaxf(acc[2*ii], 0.0f), fmaxf(acc[2*ii+1], 0.0f));
    }
#pragma unroll
    for (int ii = 0; ii < NI; ++ii) stB[nl*25 + IOFF + ii] = h2o[ii];   // h_un -> stashB
    __syncthreads();                       // B6: h_un visible; W_un stashA reads done

    // ---- h_q(own) = relu(h_un @ W_univ + b_univ) ----
    {
        float acc[2*NI];
        const float* bv = b_univ + DOFF;
#pragma unroll
        for (int ii = 0; ii < 2*NI; ++ii) acc[ii] = bv[ii];
        const float* Wv = W_univ + DOFF;
#pragma unroll
        for (int ie = 0; ie < 25; ++ie) {
            const float2 h = __half22float2(stB[nl*25 + ie]);
            const float* wr0 = Wv + (2*ie)*LDIM;
            const float* wr1 = wr0 + LDIM;
#pragma unroll
            for (int ii = 0; ii < 2*NI; ++ii)
                acc[ii] += h.x*wr0[ii] + h.y*wr1[ii];
        }
#pragma unroll
        for (int ii = 0; ii < NI; ++ii)
            h2o[ii] = __floats2half2_rn(fmaxf(acc[2*ii], 0.0f), fmaxf(acc[2*ii+1], 0.0f));
    }
#pragma unroll
    for (int ii = 0; ii < NI; ++ii) stA[nl*25 + IOFF + ii] = h2o[ii];   // h_q -> stashA
    __syncthreads();                       // B7: full h_q visible

    // ---- W_fin: own 6 chunks of 13 cols (PI=0: 0..77, PI=1: 78..154) ----
    __half2 hq2[25];
#pragma unroll
    for (int ie = 0; ie < 25; ++ie) hq2[ie] = stA[nl*25 + ie];
    float* sw = ldsf + O_SW + wave*896;                 // [64][14] per wave
    float* gbase = out + (size_t)(blockbase + pairid*64) * ODIM;
#pragma unroll
    for (int cl = 0; cl < 6; ++cl) {
        const int cg = 6*PI + cl;                        // compile-time after unroll
        const int colbase = 13*cg;
        const int NC = (cg == 11) ? 12 : 13;
        float acc[13];
#pragma unroll
        for (int o = 0; o < 13; ++o) if (o < NC) acc[o] = b_fin[colbase + o];
#pragma unroll
        for (int ie = 0; ie < 25; ++ie) {
            const float2 h = __half22float2(hq2[ie]);
            const float* wr0 = W_fin + (2*ie)*ODIM + colbase;
            const float* wr1 = wr0 + ODIM;
#pragma unroll
            for (int o = 0; o < 13; ++o) if (o < NC)
                acc[o] += h.x*wr0[o] + h.y*wr1[o];
        }
#pragma unroll
        for (int o = 0; o < 13; ++o) if (o < NC) sw[lane*14 + o] = acc[o];
        // wave-synchronous transpose read -> coalesced-ish 52B row bursts
        float* gb = gbase + colbase;
#pragma unroll
        for (int it = 0; it < 13; ++it) if (it < NC) {
            const int f = it*64 + lane;
            const int row = f / NC;
            const int col = f - row*NC;
            gb[row*ODIM + col] = sw[row*14 + col];
        }
    }
}

// ---------------------------------------------------------------------------
// Fused kernel: 1024-thr blocks (16 waves/CU — round-1-proven occupancy).
// 8 wave-pairs x 64 nodes; wave parity PI splits the 50 dims 26/24.
// Work split (not duplicated); weight streams stay wave-uniform s_loads;
// peak live ~45-65 floats -> spill-free even at a 64-VGPR allocation.
// ---------------------------------------------------------------------------
__global__ __launch_bounds__(1024, 4)
void fused_kernel(
    const float* __restrict__ oe,
    const float* __restrict__ W_bin,
    const float* __restrict__ W_un, const float* __restrict__ b_un,
    const float* __restrict__ W_univ, const float* __restrict__ b_univ,
    const float* __restrict__ W_att, const float* __restrict__ b_att,
    const float* __restrict__ W_fin, const float* __restrict__ b_fin,
    const int* __restrict__ pred_ids, const int* __restrict__ var_ids,
    const int* __restrict__ op_ids,
    const float* __restrict__ ws, float* __restrict__ out)
{
    __shared__ float ldsf[LDS_FLOATS];          // 159744 B
    __half* ldsh = (__half*)ldsf;
    const int tid = threadIdx.x;
    const int wave = tid >> 6, lane = tid & 63;
    const int pi = wave & 1, pairid = wave >> 1;
    const int nl = pairid*64 + lane;            // node-local 0..511
    const int blockbase = blockIdx.x * 512;
    const int j = blockbase + nl;               // global binary node

    // ---- stage fp16 tables + fp32 logits ----
    {
        const uint4* src = (const uint4*)ws;    // 5000 uint4 = halves [0..40000)
        uint4* dst = (uint4*)ldsh;
        for (int i = tid; i < 5000; i += 1024) dst[i] = src[i];
        if (tid < 300) ldsf[F_LG + tid] = ws[F_LG + tid];
    }
    __syncthreads();                            // B1

    const float* lgl = ldsf + F_LG;
    const float batt = b_att[0];

    int vA[5], vB[5];
    const int pA = pred_ids[2*j], pB = pred_ids[2*j+1];
#pragma unroll
    for (int s = 0; s < 5; ++s) { vA[s] = var_ids[(2*j)*5 + s]; vB[s] = var_ids[(2*j+1)*5 + s]; }
    const int op = op_ids[j];

    float ekA[5], ekB[5];
    const float e0A = __expf(lgl[pA]);
    const float e0B = __expf(lgl[pB]);
    float denA = e0A, denB = e0B;
#pragma unroll
    for (int s = 0; s < 5; ++s) {
        ekA[s] = __expf(lgl[VOCABSZ + vA[s]]); denA += ekA[s];
        ekB[s] = __expf(lgl[VOCABSZ + vB[s]]); denB += ekB[s];
    }
    const float invA = 1.0f / denA, invB = 1.0f / denB;
    const float w1 = __expf(lgl[2*VOCABSZ + op]);

    if (pi == 0)
        work<0>(nl, lane, wave, pairid, blockbase, pA, pB, vA, vB, op,
                e0A, e0B, ekA, ekB, invA, invB, w1, batt, ldsf, ldsh,
                oe, W_bin, W_un, b_un, W_univ, b_univ, W_att, W_fin, b_fin, ws, out);
    else
        work<1>(nl, lane, wave, pairid, blockbase, pA, pB, vA, vB, op,
                e0A, e0B, ekA, ekB, invA, invB, w1, batt, ldsf, ldsh,
                oe, W_bin, W_un, b_un, W_univ, b_univ, W_att, W_fin, b_fin, ws, out);
}

// ---------------------------------------------------------------------------
extern "C" void kernel_launch(void* const* d_in, const int* in_sizes, int n_in,
                              void* d_out, int out_size, void* d_ws, size_t ws_size,
                              hipStream_t stream) {
    const float* pe     = (const float*)d_in[0];
    const float* ve     = (const float*)d_in[1];
    const float* oe     = (const float*)d_in[2];
    const float* W_pred = (const float*)d_in[3];
    const float* b_pred = (const float*)d_in[4];
    const float* W_bin  = (const float*)d_in[5];
    const float* b_bin  = (const float*)d_in[6];
    const float* W_un   = (const float*)d_in[7];
    const float* b_un   = (const float*)d_in[8];
    const float* W_univ = (const float*)d_in[9];
    const float* b_univ = (const float*)d_in[10];
    const float* W_att  = (const float*)d_in[11];
    const float* b_att  = (const float*)d_in[12];
    const float* W_fin  = (const float*)d_in[13];
    const float* b_fin  = (const float*)d_in[14];
    const int* pred_ids = (const int*)d_in[15];
    const int* var_ids  = (const int*)d_in[16];
    const int* op_ids   = (const int*)d_in[17];
    float* out = (float*)d_out;
    float* ws  = (float*)d_ws;

    precompute_kernel<<<905, 64, 0, stream>>>(pe, ve, oe, W_pred, b_pred,
                                              W_bin, b_bin, W_att, b_att, ws);
    fused_kernel<<<MBIN/512, 1024, 0, stream>>>(oe, W_bin, W_un, b_un,
                                                W_univ, b_univ, W_att, b_att,
                                                W_fin, b_fin, pred_ids, var_ids,
                                                op_ids, ws, out);
}